// Round 5
// baseline (40.544 us; speedup 1.0000x reference)
//
#include <hip/hip_runtime.h>
#include <math.h>

// x: (16,3,448,448) fp32; 14x14 patches -> Hp=Wp=32; 3x3 DCT over 12x12 sliding windows
// out: (16,32,32) fp32
//
// Block = 4 consecutive patches x 3 channels = 12 patch-channels, 192 threads.
// 16 threads per pc; each thread runs 3 sliding runs of 3 windows (144/pc, exact).
// psi + entropy reduced via width-16 shfl_xor (no LDS scoreboard).
// Grid = 16*32*8 = 4096 blocks (12288 waves ~ 1.5 generations -> high occupancy).
// LDS: u8x4-packed histograms (3 KB) + 12-float combine buffer.

typedef unsigned int uint32;

__device__ __forceinline__ float fsqrt_fast(float x) { return __builtin_amdgcn_sqrtf(x); } // v_sqrt_f32
__device__ __forceinline__ float frcp_fast(float x)  { return __builtin_amdgcn_rcpf(x);  } // v_rcp_f32
__device__ __forceinline__ float flog2_fast(float x) { return __builtin_amdgcn_logf(x);  } // v_log_f32

__device__ __forceinline__ float std3_fast(float a, float b, float c) {
    // ddof=0 std of 3 via E[x^2]-E[x]^2 (clamped)
    float s = a + b + c;
    float q = fmaf(a, a, fmaf(b, b, c * c));
    float v = fmaf(q, (1.0f / 3.0f), (s * s) * (-1.0f / 9.0f));
    return fsqrt_fast(fmaxf(v, 0.0f));
}

__global__ __launch_bounds__(192, 8) void richness_kernel(
    const float* __restrict__ x,
    const float* __restrict__ dctm,
    float* __restrict__ out)
{
    const int bid = blockIdx.x;       // b*256 + hp*8 + wpg
    const int wpg = bid & 7;          // group of 4 patches along wp
    const int hp  = (bid >> 3) & 31;
    const int b   = bid >> 8;
    const int tid = threadIdx.x;

    __shared__ uint32 hist[3][256];   // per channel; 4 patches u8-packed per word (max 196)
    __shared__ float  richAcc[12];

    // DCT structure: row0 = k0*(1,1,1); row1 = k1*(1,0,-1) (D[1][1]~6e-17); row2 = k2*(1,-2,1)
    const float k0 = dctm[0];
    const float k1 = dctm[3];
    const float k2 = dctm[6];

    for (int i = tid; i < 768; i += 192) ((uint32*)hist)[i] = 0u;
    __syncthreads();

    // ---- coalesced histogram pass (also warms L1/L2) ----
    for (int t = tid; t < 588; t += 192) {           // 3ch * 14 rows * 14 float4
        int chh = t / 196;
        int rem = t - chh * 196;
        int row = rem / 14;
        int col = (rem - row * 14) * 4;
        const float* src = x + (((size_t)(b * 3 + chh) * 448 + hp * 14 + row) * 448) + wpg * 56 + col;
        float4 v = *reinterpret_cast<const float4*>(src);
#pragma unroll
        for (int e = 0; e < 4; ++e) {
            float val = (&v.x)[e];
            int bin = (int)rintf(val * 255.0f);      // round-half-even == np.round
            bin = min(max(bin, 0), 255);
            int ce = col + e;
            int p  = (ce * 2341) >> 15;              // ce/14 for ce<56
            atomicAdd(&hist[chh][bin], 1u << (p * 8));
        }
    }
    // no sync needed: window pass doesn't touch hist

    // ---- sliding windows: 16 threads/pc, 3 runs of 3 windows each ----
    const int pc = tid >> 4;          // 0..11
    const int s  = tid & 15;          // 0..15
    const int ch = pc >> 2, p = pc & 3;

    float psi3 = 0.0f;
#pragma unroll
    for (int kq = 0; kq < 3; ++kq) {
        int r  = s + 16 * kq;         // 0..47
        int wi = r >> 2;              // 0..11
        int j0 = (r & 3) * 3;         // 0,3,6,9
        const float* base = x + (((size_t)(b * 3 + ch) * 448 + hp * 14 + wi) * 448)
                              + wpg * 56 + p * 14 + j0;

        // 3 rows x 5 cols scalar loads; offsets fold to load immediates (<3616B)
        float t0[5], t1[5], t2[5];
#pragma unroll
        for (int c = 0; c < 5; ++c) {
            float a  = base[c];
            float bb = base[448 + c];
            float cv = base[896 + c];
            float ss = a + cv;
            t0[c] = k0 * (ss + bb);
            t1[c] = k1 * (a - cv);
            t2[c] = k2 * fmaf(-2.0f, bb, ss);
        }

#pragma unroll
        for (int m = 0; m < 3; ++m) {
            float X0 = t0[m],     X1 = t1[m],     X2 = t2[m];
            float Y0 = t0[m + 1], Y1 = t1[m + 1], Y2 = t2[m + 1];
            float Z0 = t0[m + 2], Z1 = t1[m + 2], Z2 = t2[m + 2];
            float xz0 = X0 + Z0, xz1 = X1 + Z1, xz2 = X2 + Z2;
            float d00 = k0 * (xz0 + Y0), d01 = k1 * (X0 - Z0), d02 = k2 * fmaf(-2.0f, Y0, xz0);
            float d10 = k0 * (xz1 + Y1), d11 = k1 * (X1 - Z1), d12 = k2 * fmaf(-2.0f, Y1, xz1);
            float d20 = k0 * (xz2 + Y2), d21 = k1 * (X2 - Z2), d22 = k2 * fmaf(-2.0f, Y2, xz2);

            float S1 = (std3_fast(d00, d01, d02) + std3_fast(d10, d11, d12) + std3_fast(d20, d21, d22)) * (1.0f / 3.0f);
            float S2 = (std3_fast(d00, d10, d20) + std3_fast(d01, d11, d21) + std3_fast(d02, d12, d22)) * (1.0f / 3.0f);
            float S3 = std3_fast(d00, d11, d22);
            float S4 = std3_fast(d02, d11, d20);

            float sumS = (S1 + S2) + (S3 + S4);
            float sumQ = fmaf(S1, S1, fmaf(S2, S2, fmaf(S3, S3, S4 * S4)));
            float h    = fmaxf(fmaf(-0.25f * sumS, sumS, sumQ), 0.0f);
            float Sm   = fmaf(sumS, 0.25f, 1e-8f);
            float inv  = frcp_fast(Sm);
            psi3       = fmaf(h * inv * inv, (1.0f / 3.0f), psi3);
        }
    }

    // psi total for this pc -> all 16 lanes of the group
#pragma unroll
    for (int off = 1; off < 16; off <<= 1) psi3 += __shfl_xor(psi3, off, 64);

    __syncthreads();   // hist atomics drained

    // ---- entropy: same 16-thread groups, 16 bins each ----
    {
        float negent = 0.0f;
        const int sh = p * 8;
#pragma unroll
        for (int kk = 0; kk < 16; ++kk) {
            uint32 c = (hist[ch][s + 16 * kk] >> sh) & 0xffu;
            float pr = (float)c * (1.0f / 196.0f) + 1e-10f;
            negent = fmaf(pr, flog2_fast(pr), negent);
        }
#pragma unroll
        for (int off = 1; off < 16; off <<= 1) negent += __shfl_xor(negent, off, 64);
        if (s == 0) richAcc[pc] = (psi3 * (1.0f / 144.0f)) * (-negent);
    }
    __syncthreads();

    // ---- channel mean -> out ----
    if (tid < 4) {
        float rv = (richAcc[tid] + richAcc[4 + tid] + richAcc[8 + tid]) * (1.0f / 3.0f);
        out[(b * 32 + hp) * 32 + wpg * 4 + tid] = rv;
    }
}

extern "C" void kernel_launch(void* const* d_in, const int* in_sizes, int n_in,
                              void* d_out, int out_size, void* d_ws, size_t ws_size,
                              hipStream_t stream) {
    const float* x    = (const float*)d_in[0];
    const float* dctm = (const float*)d_in[1];
    float* out        = (float*)d_out;

    richness_kernel<<<4096, 192, 0, stream>>>(x, dctm, out);
}